// Round 6
// baseline (133.743 us; speedup 1.0000x reference)
//
#include <hip/hip_runtime.h>

#define LL   1024
#define BHD  128   // B*heads = 16*8
#define LOG2E 1.44269504088896340736f

typedef unsigned int       uint;
typedef unsigned short     ushort;
typedef unsigned long long ull;

typedef __attribute__((ext_vector_type(8))) __bf16          bf16x8;
typedef __attribute__((ext_vector_type(8))) unsigned short  u16x8;
typedef __attribute__((ext_vector_type(2))) uint            ui32x2;
typedef __attribute__((ext_vector_type(4))) uint            ui32x4;
typedef __attribute__((ext_vector_type(4))) float           f32x4;

static __device__ __forceinline__ ushort f2bf(float f){
  union {float f; uint u;} v; v.f = f;
  uint u = v.u + 0x7fffu + ((v.u >> 16) & 1u);  // RNE
  return (ushort)(u >> 16);
}
static __device__ __forceinline__ uint pack2(float a, float b){
  return (uint)f2bf(a) | ((uint)f2bf(b) << 16);
}
// truncating pack: one v_perm
static __device__ __forceinline__ uint packtrunc(float a, float b){
  union {float f; uint u;} x, y; x.f = a; y.f = b;
  return __builtin_amdgcn_perm(y.u, x.u, 0x07060302u);
}
static __device__ __forceinline__ bf16x8 ld_frag(const ushort* p){
  u16x8 t = *(const u16x8*)p;
  return __builtin_bit_cast(bf16x8, t);
}

// bf16 vs fp32 sniff on x (deterministic, graph-safe).
static __device__ __forceinline__ bool sniff_is_bf16(const uint* xw, int tid, int* cnt){
  uint w = xw[tid & 255];
  uint e = (w >> 7) & 0xFFu;
  bool hit = (e >= 118u) && (e <= 132u);
  ull b = __ballot(hit);
  if ((tid & 63) == 0) cnt[tid >> 6] = __popcll(b);
  __syncthreads();
  bool r = (cnt[0] + cnt[1] + cnt[2] + cnt[3]) > 128;
  __syncthreads();
  return r;
}

// ---------------------------------------------------------------------------
// Kernel 1: grouped 1x1 conv via MFMA.
// Q (D[m=l][n=d]) -> Qt[bh][l][32]  (attn loads Q frags contiguous)
// K,V (D[m=d][n=l], swapped operands) -> Kt,Vt[bh][d][1024] (d-major,
// coalesced stores; attn stages rows coalesced). K gets PE then *log2e.
// ---------------------------------------------------------------------------
__global__ __launch_bounds__(256) void qkv_kernel(
    const void* __restrict__ xr,
    const void* __restrict__ wqr,
    const void* __restrict__ wkr,
    const void* __restrict__ wvr,
    ushort* __restrict__ Qt, ushort* __restrict__ Kt, ushort* __restrict__ Vt)
{
  const int bh   = blockIdx.x;
  const int lt   = blockIdx.y;          // 0..7, 128-l tiles
  const int tid  = threadIdx.x;
  const int wave = tid >> 6;
  const int lane = tid & 63;
  const int l16  = lane & 15;
  const int quad = lane >> 4;
  const int lbase = lt * 128;

  __shared__ int cnt[4];
  // xsd[l][cp]: dword cp = channels (2cp, 2cp+1). 80B rows.
  __shared__ __align__(16) uint xsd[128][20];

  const bool is_bf = sniff_is_bf16((const uint*)xr, tid, cnt);

  { // stage + transpose x tile: thread = (c-pair, 8-l group)
    const int cp = tid & 15, lg = tid >> 4;
    const size_t rb = (size_t)(bh*32 + 2*cp)*LL + lbase + lg*8;
    uint dw[8];
    if (is_bf){
      u16x8 e = *(const u16x8*)((const ushort*)xr + rb);
      u16x8 o = *(const u16x8*)((const ushort*)xr + rb + LL);
      #pragma unroll
      for (int j = 0; j < 8; ++j) dw[j] = (uint)e[j] | ((uint)o[j] << 16);
    } else {
      const float* xf = (const float*)xr;
      float4 e0 = *(const float4*)(xf + rb);
      float4 e1 = *(const float4*)(xf + rb + 4);
      float4 o0 = *(const float4*)(xf + rb + LL);
      float4 o1 = *(const float4*)(xf + rb + LL + 4);
      dw[0]=pack2(e0.x,o0.x); dw[1]=pack2(e0.y,o0.y);
      dw[2]=pack2(e0.z,o0.z); dw[3]=pack2(e0.w,o0.w);
      dw[4]=pack2(e1.x,o1.x); dw[5]=pack2(e1.y,o1.y);
      dw[6]=pack2(e1.z,o1.z); dw[7]=pack2(e1.w,o1.w);
    }
    #pragma unroll
    for (int j = 0; j < 8; ++j) xsd[lg*8 + j][cp] = dw[j];
  }
  __syncthreads();

  // W fragments: lane index = row nh*16+l16, k = c = quad*8+j
  const void* wsrc[3] = {wqr, wkr, wvr};
  bf16x8 bw[3][2];
  #pragma unroll
  for (int p = 0; p < 3; ++p)
    #pragma unroll
    for (int nh = 0; nh < 2; ++nh){
      const int row = (bh & 7)*32 + nh*16 + l16;
      if (is_bf){
        bw[p][nh] = ld_frag((const ushort*)wsrc[p] + (size_t)row*32 + quad*8);
      } else {
        const float* wf = (const float*)wsrc[p] + (size_t)row*32 + quad*8;
        float4 f0 = *(const float4*)wf, f1 = *(const float4*)(wf + 4);
        u16x8 t;
        t[0]=f2bf(f0.x); t[1]=f2bf(f0.y); t[2]=f2bf(f0.z); t[3]=f2bf(f0.w);
        t[4]=f2bf(f1.x); t[5]=f2bf(f1.y); t[6]=f2bf(f1.z); t[7]=f2bf(f1.w);
        bw[p][nh] = __builtin_bit_cast(bf16x8, t);
      }
    }

  // x^T fragments: l = wave*32 + mt*16 + l16, k = quad*8+j
  bf16x8 ax[2];
  #pragma unroll
  for (int mt = 0; mt < 2; ++mt)
    ax[mt] = __builtin_bit_cast(bf16x8,
               *(const ui32x4*)&xsd[wave*32 + mt*16 + l16][quad*4]);

  const f32x4 z = {0.f,0.f,0.f,0.f};
  f32x4 dq[2][2], dk[2][2], dv[2][2];
  #pragma unroll
  for (int mt = 0; mt < 2; ++mt)
    #pragma unroll
    for (int nh = 0; nh < 2; ++nh){
      dq[mt][nh] = __builtin_amdgcn_mfma_f32_16x16x32_bf16(ax[mt], bw[0][nh], z, 0,0,0);
      dk[nh][mt] = __builtin_amdgcn_mfma_f32_16x16x32_bf16(bw[1][nh], ax[mt], z, 0,0,0);
      dv[nh][mt] = __builtin_amdgcn_mfma_f32_16x16x32_bf16(bw[2][nh], ax[mt], z, 0,0,0);
    }

  // Q stores: lane holds l = quad*4+r, d = nh*16+l16 -> Qt[l][d]
  #pragma unroll
  for (int mt = 0; mt < 2; ++mt)
    #pragma unroll
    for (int nh = 0; nh < 2; ++nh)
      #pragma unroll
      for (int r = 0; r < 4; ++r){
        const int l = lbase + wave*32 + mt*16 + quad*4 + r;
        const int d = nh*16 + l16;
        Qt[((size_t)bh*LL + l)*32 + d] = f2bf(dq[mt][nh][r]);
      }
  // K stores (d-major): lane holds d = dh*16+quad*4+r, l = mt*16+l16
  #pragma unroll
  for (int dh = 0; dh < 2; ++dh)
    #pragma unroll
    for (int r = 0; r < 4; ++r){
      const int d = dh*16 + quad*4 + r;
      const int c = (bh & 7)*32 + d;
      const float freq = __expf(-0.03597789207f * (float)(c & ~1));
      #pragma unroll
      for (int mt = 0; mt < 2; ++mt){
        const int l = lbase + wave*32 + mt*16 + l16;
        const float ang = freq * (float)l;
        const float pe  = (c & 1) ? __cosf(ang) : __sinf(ang);
        Kt[((size_t)(bh*32 + d))*LL + l] = f2bf((dk[dh][mt][r] + pe) * LOG2E);
      }
    }
  // V stores (d-major)
  #pragma unroll
  for (int dh = 0; dh < 2; ++dh)
    #pragma unroll
    for (int mt = 0; mt < 2; ++mt)
      #pragma unroll
      for (int r = 0; r < 4; ++r){
        const int d = dh*16 + quad*4 + r;
        const int l = lbase + wave*32 + mt*16 + l16;
        Vt[((size_t)(bh*32 + d))*LL + l] = f2bf(dv[dh][mt][r]);
      }
}

// ---------------------------------------------------------------------------
// Kernel 2: flash attention. Block = (bh, 128-q tile), 4 waves x 32 q.
// Double-buffered K/V staging (1 barrier/kt), wave-specialized staging
// (waves 0-1: K transpose-pack, waves 2-3: V). No-max exp2 softmax.
// S^T = K^T*Q; P enters PV as A-operand via wave-private LDS round-trip.
// ---------------------------------------------------------------------------
__global__ __launch_bounds__(256, 4) void attn_kernel(
    const void*   __restrict__ xr,     // dtype sniff only (output format)
    const ushort* __restrict__ Qt,
    const ushort* __restrict__ Kt,
    const ushort* __restrict__ Vt,
    void* __restrict__ out)
{
  const int bh   = blockIdx.x;
  const int qt   = blockIdx.y;          // 0..7 (128 q per block)
  const int tid  = threadIdx.x;
  const int wave = tid >> 6;
  const int lane = tid & 63;
  const int l16  = lane & 15;
  const int quad = lane >> 4;

  __shared__ int cnt[4];
  __shared__ __align__(16) uint   Ksd[2][64][20];  // dword c-pairs, 80B rows
  __shared__ __align__(16) ushort Vs [2][32][72];  // 144B rows
  __shared__ __align__(16) uint   Psd[4][32][36];  // wave-private P, 144B rows

  const bool is_bf = sniff_is_bf16((const uint*)xr, tid, cnt);

  // Q fragments (B operand): n = q, k = d = quad*8+j; two q-halves per lane
  bf16x8 bq[2];
  #pragma unroll
  for (int h = 0; h < 2; ++h){
    const int qg = qt*128 + wave*32 + h*16 + l16;
    bq[h] = __builtin_bit_cast(bf16x8,
              *((const ui32x4*)(Qt + ((size_t)bh*LL + qg)*32) + quad));
  }

  // staging roles
  const int dp = tid >> 3, kg = tid & 7;          // waves 0-1: K c-pair rows
  const int vd = (tid - 128) >> 3, vg = tid & 7;  // waves 2-3: V rows vd, vd+16
  const ushort* kbase = Kt + (size_t)bh*32*LL;
  const ushort* vbase = Vt + (size_t)bh*32*LL;

  u16x8 se, so, sv0, sv1;
  const bool kstage = (tid < 128);

  // prologue: kt = 0
  if (kstage){
    const ushort* p0 = kbase + (size_t)(2*dp)*LL + kg*8;
    se = *(const u16x8*)p0;
    so = *(const u16x8*)(p0 + LL);
  } else {
    sv0 = *(const u16x8*)(vbase + (size_t)vd*LL + vg*8);
    sv1 = *(const u16x8*)(vbase + (size_t)(vd+16)*LL + vg*8);
  }
  if (kstage){
    #pragma unroll
    for (int j = 0; j < 8; ++j)
      Ksd[0][kg*8 + j][dp] = (uint)se[j] | ((uint)so[j] << 16);
  } else {
    *(u16x8*)&Vs[0][vd][vg*8]      = sv0;
    *(u16x8*)&Vs[0][vd + 16][vg*8] = sv1;
  }
  __syncthreads();

  f32x4 accO[2][2];
  #pragma unroll
  for (int h = 0; h < 2; ++h)
    #pragma unroll
    for (int dh = 0; dh < 2; ++dh) accO[h][dh] = (f32x4){0.f,0.f,0.f,0.f};
  float rsum[2] = {0.f, 0.f};

  for (int kt = 0; kt < 16; ++kt){
    const int cur = kt & 1;

    if (kt < 15){   // prefetch kt+1 into registers
      const int ko = (kt + 1)*64;
      if (kstage){
        const ushort* p0 = kbase + (size_t)(2*dp)*LL + ko + kg*8;
        se = *(const u16x8*)p0;
        so = *(const u16x8*)(p0 + LL);
      } else {
        sv0 = *(const u16x8*)(vbase + (size_t)vd*LL + ko + vg*8);
        sv1 = *(const u16x8*)(vbase + (size_t)(vd+16)*LL + ko + vg*8);
      }
    }

    // S^T: M=key (4x16), N=q (2x16), K=32 (K already *log2e)
    const f32x4 z = {0.f,0.f,0.f,0.f};
    f32x4 st[2][4];
    #pragma unroll
    for (int mt = 0; mt < 4; ++mt){
      bf16x8 ka = __builtin_bit_cast(bf16x8,
                    *(const ui32x4*)&Ksd[cur][mt*16 + l16][quad*4]);
      st[0][mt] = __builtin_amdgcn_mfma_f32_16x16x32_bf16(ka, bq[0], z, 0,0,0);
      st[1][mt] = __builtin_amdgcn_mfma_f32_16x16x32_bf16(ka, bq[1], z, 0,0,0);
    }

    // softmax (no max): p = exp2(s)
    #pragma unroll
    for (int h = 0; h < 2; ++h)
      #pragma unroll
      for (int mt = 0; mt < 4; ++mt)
        #pragma unroll
        for (int r = 0; r < 4; ++r){
          float p = exp2f(st[h][mt][r]);
          st[h][mt][r] = p;
          rsum[h] += p;
        }

    // P -> LDS (wave-private, b64 writes)
    #pragma unroll
    for (int h = 0; h < 2; ++h)
      #pragma unroll
      for (int mt = 0; mt < 4; ++mt){
        ui32x2 pk;
        pk[0] = packtrunc(st[h][mt][0], st[h][mt][1]);
        pk[1] = packtrunc(st[h][mt][2], st[h][mt][3]);
        *(ui32x2*)&Psd[wave][h*16 + l16][mt*8 + quad*2] = pk;
      }

    // O += P*V^T : V frags shared across both q-halves
    #pragma unroll
    for (int c = 0; c < 2; ++c){
      bf16x8 b0 = ld_frag(&Vs[cur][l16     ][c*32 + quad*8]);
      bf16x8 b1 = ld_frag(&Vs[cur][16 + l16][c*32 + quad*8]);
      #pragma unroll
      for (int h = 0; h < 2; ++h){
        bf16x8 pa = __builtin_bit_cast(bf16x8,
                      *(const ui32x4*)&Psd[wave][h*16 + l16][c*16 + quad*4]);
        accO[h][0] = __builtin_amdgcn_mfma_f32_16x16x32_bf16(pa, b0, accO[h][0], 0,0,0);
        accO[h][1] = __builtin_amdgcn_mfma_f32_16x16x32_bf16(pa, b1, accO[h][1], 0,0,0);
      }
    }

    if (kt < 15){   // write prefetched tile to the other buffer
      const int nb = cur ^ 1;
      if (kstage){
        #pragma unroll
        for (int j = 0; j < 8; ++j)
          Ksd[nb][kg*8 + j][dp] = (uint)se[j] | ((uint)so[j] << 16);
      } else {
        *(u16x8*)&Vs[nb][vd][vg*8]      = sv0;
        *(u16x8*)&Vs[nb][vd + 16][vg*8] = sv1;
      }
    }
    __syncthreads();
  }

  // final l reduction per q-half
  #pragma unroll
  for (int h = 0; h < 2; ++h){
    rsum[h] += __shfl_xor(rsum[h], 16);
    rsum[h] += __shfl_xor(rsum[h], 32);
  }

  // epilogue: out[(bh*32 + d)*1024 + q]
  #pragma unroll
  for (int h = 0; h < 2; ++h)
    #pragma unroll
    for (int r = 0; r < 4; r += 2){
      float l0 = __shfl(rsum[h], quad*4 + r);
      float l1 = __shfl(rsum[h], quad*4 + r + 1);
      float i0 = 1.f / l0, i1 = 1.f / l1;
      const int q = qt*128 + wave*32 + h*16 + quad*4 + r;
      #pragma unroll
      for (int dh = 0; dh < 2; ++dh){
        float a0 = accO[h][dh][r]*i0, a1 = accO[h][dh][r+1]*i1;
        const size_t off = ((size_t)(bh*32 + dh*16 + l16))*LL + q;
        if (is_bf) *(uint*)((ushort*)out + off) = pack2(a0, a1);
        else       *(float2*)((float*)out + off) = make_float2(a0, a1);
      }
    }
}

extern "C" void kernel_launch(void* const* d_in, const int* in_sizes, int n_in,
                              void* d_out, int out_size, void* d_ws, size_t ws_size,
                              hipStream_t stream) {
  const void* x  = d_in[0];
  const void* wq = d_in[1];
  const void* wk = d_in[2];
  const void* wv = d_in[3];

  ushort* Qt = (ushort*)d_ws;                    // bf16 workspace
  ushort* Kt = Qt + (size_t)BHD * LL * 32;
  ushort* Vt = Kt + (size_t)BHD * LL * 32;

  qkv_kernel <<<dim3(BHD, 8), 256, 0, stream>>>(x, wq, wk, wv, Qt, Kt, Vt);
  attn_kernel<<<dim3(BHD, 8), 256, 0, stream>>>(x, Qt, Kt, Vt, d_out);
}

// Round 7
// 127.950 us; speedup vs baseline: 1.0453x; 1.0453x over previous
//
#include <hip/hip_runtime.h>

#define LL   1024
#define BHD  128   // B*heads = 16*8
#define LOG2E 1.44269504088896340736f

typedef unsigned int       uint;
typedef unsigned short     ushort;
typedef unsigned long long ull;

typedef __attribute__((ext_vector_type(8)))  __bf16          bf16x8;
typedef __attribute__((ext_vector_type(8)))  unsigned short  u16x8;
typedef __attribute__((ext_vector_type(4)))  uint            ui32x4;
typedef __attribute__((ext_vector_type(4)))  float           f32x4;
typedef __attribute__((ext_vector_type(16))) float           f32x16;

static __device__ __forceinline__ ushort f2bf(float f){
  union {float f; uint u;} v; v.f = f;
  uint u = v.u + 0x7fffu + ((v.u >> 16) & 1u);  // RNE
  return (ushort)(u >> 16);
}
static __device__ __forceinline__ uint pack2(float a, float b){
  return (uint)f2bf(a) | ((uint)f2bf(b) << 16);
}
// truncating pack: one v_perm
static __device__ __forceinline__ uint packtrunc(float a, float b){
  union {float f; uint u;} x, y; x.f = a; y.f = b;
  return __builtin_amdgcn_perm(y.u, x.u, 0x07060302u);
}
static __device__ __forceinline__ bf16x8 ld_frag(const ushort* p){
  u16x8 t = *(const u16x8*)p;
  return __builtin_bit_cast(bf16x8, t);
}

// bf16 vs fp32 sniff on x (deterministic, graph-safe).
static __device__ __forceinline__ bool sniff_is_bf16(const uint* xw, int tid, int* cnt){
  uint w = xw[tid & 255];
  uint e = (w >> 7) & 0xFFu;
  bool hit = (e >= 118u) && (e <= 132u);
  ull b = __ballot(hit);
  if ((tid & 63) == 0) cnt[tid >> 6] = __popcll(b);
  __syncthreads();
  bool r = (cnt[0] + cnt[1] + cnt[2] + cnt[3]) > 128;
  __syncthreads();
  return r;
}

// ---------------------------------------------------------------------------
// Kernel 1: grouped 1x1 conv via MFMA.
// Q (D[m=l][n=d]) -> Qt[bh][l][32]  key-major
// K (D[m=l][n=d]) -> Kt[bh][l][32]  key-major, + PE, *log2e
// V (D[m=d][n=l], swapped operands) -> Vt[bh][d][1024] d-major
// ---------------------------------------------------------------------------
__global__ __launch_bounds__(256) void qkv_kernel(
    const void* __restrict__ xr,
    const void* __restrict__ wqr,
    const void* __restrict__ wkr,
    const void* __restrict__ wvr,
    ushort* __restrict__ Qt, ushort* __restrict__ Kt, ushort* __restrict__ Vt)
{
  const int bh   = blockIdx.x;
  const int lt   = blockIdx.y;          // 0..7, 128-l tiles
  const int tid  = threadIdx.x;
  const int wave = tid >> 6;
  const int lane = tid & 63;
  const int l16  = lane & 15;
  const int quad = lane >> 4;
  const int lbase = lt * 128;

  __shared__ int cnt[4];
  __shared__ __align__(16) uint xsd[128][20];   // dword c-pairs, 80B rows

  const bool is_bf = sniff_is_bf16((const uint*)xr, tid, cnt);

  { // stage + transpose x tile: thread = (c-pair, 8-l group)
    const int cp = tid & 15, lg = tid >> 4;
    const size_t rb = (size_t)(bh*32 + 2*cp)*LL + lbase + lg*8;
    uint dw[8];
    if (is_bf){
      u16x8 e = *(const u16x8*)((const ushort*)xr + rb);
      u16x8 o = *(const u16x8*)((const ushort*)xr + rb + LL);
      #pragma unroll
      for (int j = 0; j < 8; ++j) dw[j] = (uint)e[j] | ((uint)o[j] << 16);
    } else {
      const float* xf = (const float*)xr;
      float4 e0 = *(const float4*)(xf + rb);
      float4 e1 = *(const float4*)(xf + rb + 4);
      float4 o0 = *(const float4*)(xf + rb + LL);
      float4 o1 = *(const float4*)(xf + rb + LL + 4);
      dw[0]=pack2(e0.x,o0.x); dw[1]=pack2(e0.y,o0.y);
      dw[2]=pack2(e0.z,o0.z); dw[3]=pack2(e0.w,o0.w);
      dw[4]=pack2(e1.x,o1.x); dw[5]=pack2(e1.y,o1.y);
      dw[6]=pack2(e1.z,o1.z); dw[7]=pack2(e1.w,o1.w);
    }
    #pragma unroll
    for (int j = 0; j < 8; ++j) xsd[lg*8 + j][cp] = dw[j];
  }
  __syncthreads();

  const void* wsrc[3] = {wqr, wkr, wvr};
  bf16x8 bw[3][2];
  #pragma unroll
  for (int p = 0; p < 3; ++p)
    #pragma unroll
    for (int nh = 0; nh < 2; ++nh){
      const int row = (bh & 7)*32 + nh*16 + l16;
      if (is_bf){
        bw[p][nh] = ld_frag((const ushort*)wsrc[p] + (size_t)row*32 + quad*8);
      } else {
        const float* wf = (const float*)wsrc[p] + (size_t)row*32 + quad*8;
        float4 f0 = *(const float4*)wf, f1 = *(const float4*)(wf + 4);
        u16x8 t;
        t[0]=f2bf(f0.x); t[1]=f2bf(f0.y); t[2]=f2bf(f0.z); t[3]=f2bf(f0.w);
        t[4]=f2bf(f1.x); t[5]=f2bf(f1.y); t[6]=f2bf(f1.z); t[7]=f2bf(f1.w);
        bw[p][nh] = __builtin_bit_cast(bf16x8, t);
      }
    }

  bf16x8 ax[2];
  #pragma unroll
  for (int mt = 0; mt < 2; ++mt)
    ax[mt] = __builtin_bit_cast(bf16x8,
               *(const ui32x4*)&xsd[wave*32 + mt*16 + l16][quad*4]);

  const f32x4 z = {0.f,0.f,0.f,0.f};
  f32x4 dq[2][2], dk[2][2], dv[2][2];
  #pragma unroll
  for (int mt = 0; mt < 2; ++mt)
    #pragma unroll
    for (int nh = 0; nh < 2; ++nh){
      dq[mt][nh] = __builtin_amdgcn_mfma_f32_16x16x32_bf16(ax[mt], bw[0][nh], z, 0,0,0);
      dk[mt][nh] = __builtin_amdgcn_mfma_f32_16x16x32_bf16(ax[mt], bw[1][nh], z, 0,0,0);
      dv[nh][mt] = __builtin_amdgcn_mfma_f32_16x16x32_bf16(bw[2][nh], ax[mt], z, 0,0,0);
    }

  // Q stores: lane holds l = quad*4+r, d = nh*16+l16 -> Qt[l][d]
  #pragma unroll
  for (int mt = 0; mt < 2; ++mt)
    #pragma unroll
    for (int nh = 0; nh < 2; ++nh)
      #pragma unroll
      for (int r = 0; r < 4; ++r){
        const int l = lbase + wave*32 + mt*16 + quad*4 + r;
        const int d = nh*16 + l16;
        Qt[((size_t)bh*LL + l)*32 + d] = f2bf(dq[mt][nh][r]);
      }
  // K stores (key-major): + sine PE (fp32), then *log2e
  #pragma unroll
  for (int mt = 0; mt < 2; ++mt)
    #pragma unroll
    for (int nh = 0; nh < 2; ++nh){
      const int d = nh*16 + l16;
      const int c = (bh & 7)*32 + d;
      const float freq = __expf(-0.03597789207f * (float)(c & ~1));
      #pragma unroll
      for (int r = 0; r < 4; ++r){
        const int l = lbase + wave*32 + mt*16 + quad*4 + r;
        const float ang = freq * (float)l;
        const float pe  = (c & 1) ? __cosf(ang) : __sinf(ang);
        Kt[((size_t)bh*LL + l)*32 + d] = f2bf((dk[mt][nh][r] + pe) * LOG2E);
      }
    }
  // V stores (d-major)
  #pragma unroll
  for (int dh = 0; dh < 2; ++dh)
    #pragma unroll
    for (int mt = 0; mt < 2; ++mt)
      #pragma unroll
      for (int r = 0; r < 4; ++r){
        const int d = dh*16 + quad*4 + r;
        const int l = lbase + wave*32 + mt*16 + l16;
        Vt[((size_t)(bh*32 + d))*LL + l] = f2bf(dv[dh][mt][r]);
      }
}

// ---------------------------------------------------------------------------
// Kernel 2: flash attention on 32x32x16 MFMAs. Block = (bh, 128-q), 4 waves
// x 32 q. S^T tiles (M=32 keys, N=32 q): C col = lane&31 = q. P reaches the
// PV B-operand (k=8h+j) via ONE half-wave shfl_xor(32) exchange per 16-key
// chunk — no P LDS round-trip at all. O^T = V*P^T: epilogue & rsum are
// lane-local in q and output stores are coalesced. No-max exp2 softmax.
// Ks seg-rotated (read banks provably uniform), Vs 144B pitch (uniform).
// ---------------------------------------------------------------------------
__global__ __launch_bounds__(256, 4) void attn_kernel(
    const void*   __restrict__ xr,     // dtype sniff only (output format)
    const ushort* __restrict__ Qt,
    const ushort* __restrict__ Kt,
    const ushort* __restrict__ Vt,
    void* __restrict__ out)
{
  const int bh  = blockIdx.x;
  const int qt  = blockIdx.y;          // 0..7 (128 q per block)
  const int tid = threadIdx.x;
  const int wave = tid >> 6;
  const int lane = tid & 63;
  const int q32  = lane & 31;
  const int h    = lane >> 5;

  __shared__ int cnt[4];
  __shared__ __align__(16) ushort Ks[64][40];   // 80B rows, seg-rotated
  __shared__ __align__(16) ushort Vs[32][72];   // 144B rows

  const bool is_bf = sniff_is_bf16((const uint*)xr, tid, cnt);

  // Q B-frags: n = q = lane&31, k = c*16 + 8h + j
  const int qg = qt*128 + wave*32 + q32;
  const ushort* qrow = Qt + ((size_t)bh*LL + qg)*32;
  bf16x8 bq0 = ld_frag(qrow + h*8);
  bf16x8 bq1 = ld_frag(qrow + 16 + h*8);

  // staging: K: thread=(key 0..63, seg 0..3); V: thread=(d 0..31, g 0..7)
  const int skey = tid >> 2, sseg = tid & 3;
  const int sp = (sseg + (skey >> 2)) & 3;             // seg rotation
  const ushort* kg = Kt + ((size_t)(bh*LL + skey))*32 + sseg*8;
  ushort* kw = &Ks[skey][sp*8];
  const int sd = tid >> 3, sg = tid & 7;
  const ushort* vg = Vt + ((size_t)(bh*32 + sd))*LL + sg*8;
  ushort* vw = &Vs[sd][sg*8];

  // A-frag read pointers (rotation matches write: rot = (row>>2)&3)
  const int rot = (q32 >> 2) & 3;
  const ushort* ka0 = &Ks[q32][((h + rot) & 3)*8];       // c'=0
  const ushort* ka1 = &Ks[q32][((2 + h + rot) & 3)*8];   // c'=1
  const ushort* vr  = &Vs[q32][h*8];                     // + 16*c per chunk

  f32x16 O = {};
  float rsum = 0.f;

  u16x8 kreg = *(const u16x8*)kg;
  u16x8 vreg = *(const u16x8*)vg;

  for (int kt = 0; kt < 16; ++kt){
    __syncthreads();                 // previous tile fully consumed
    *(u16x8*)kw = kreg;
    *(u16x8*)vw = vreg;
    __syncthreads();                 // tile kt ready
    if (kt < 15){                    // prefetch kt+1 (hidden by compute)
      kreg = *(const u16x8*)(kg + (size_t)(kt+1)*64*32);
      vreg = *(const u16x8*)(vg + (kt+1)*64);
    }

    // S^T: D[m=key][n=q], 2 tiles of 32 keys, K=32 via 2 chained MFMAs
    f32x16 st[2];
    #pragma unroll
    for (int t = 0; t < 2; ++t){
      bf16x8 a0 = ld_frag(ka0 + t*32*40);
      bf16x8 a1 = ld_frag(ka1 + t*32*40);
      f32x16 zz = {};
      f32x16 s  = __builtin_amdgcn_mfma_f32_32x32x16_bf16(a0, bq0, zz, 0,0,0);
      st[t]     = __builtin_amdgcn_mfma_f32_32x32x16_bf16(a1, bq1, s,  0,0,0);
    }

    // softmax (no max; scores*log2e bounded << 127): p = exp2(s)
    uint pr[2][8];
    #pragma unroll
    for (int t = 0; t < 2; ++t)
      #pragma unroll
      for (int zi = 0; zi < 8; ++zi){
        float p0 = exp2f(st[t][2*zi]);
        float p1 = exp2f(st[t][2*zi+1]);
        rsum += p0 + p1;
        pr[t][zi] = packtrunc(p0, p1);
      }

    // O^T += V * P^T over 4 chunks of 16 keys
    #pragma unroll
    for (int c = 0; c < 4; ++c){
      const int t = c >> 1, g0 = 4*(c & 1);
      uint s0 = h ? pr[t][g0+0] : pr[t][g0+2];
      uint s1 = h ? pr[t][g0+1] : pr[t][g0+3];
      uint r0 = (uint)__shfl_xor((int)s0, 32);
      uint r1 = (uint)__shfl_xor((int)s1, 32);
      ui32x4 pb;
      pb[0] = h ? r0 : pr[t][g0+0];
      pb[1] = h ? r1 : pr[t][g0+1];
      pb[2] = h ? pr[t][g0+2] : r0;
      pb[3] = h ? pr[t][g0+3] : r1;
      bf16x8 va = ld_frag(vr + c*16);
      O = __builtin_amdgcn_mfma_f32_32x32x16_bf16(
            va, __builtin_bit_cast(bf16x8, pb), O, 0,0,0);
    }
  }

  // lane holds keys with bit2==h; partner holds the rest
  rsum += __shfl_xor(rsum, 32);
  const float inv = 1.f / rsum;

  // epilogue: D[m=d][n=q]: d = (reg&3)+8(reg>>2)+4h, q = lane&31 (coalesced)
  #pragma unroll
  for (int reg = 0; reg < 16; ++reg){
    const int d = (reg & 3) + 8*(reg >> 2) + 4*h;
    const float v = O[reg] * inv;
    const size_t off = ((size_t)(bh*32 + d))*LL + qg;
    if (is_bf) ((ushort*)out)[off] = f2bf(v);
    else       ((float*)out)[off]  = v;
  }
}

extern "C" void kernel_launch(void* const* d_in, const int* in_sizes, int n_in,
                              void* d_out, int out_size, void* d_ws, size_t ws_size,
                              hipStream_t stream) {
  const void* x  = d_in[0];
  const void* wq = d_in[1];
  const void* wk = d_in[2];
  const void* wv = d_in[3];

  ushort* Qt = (ushort*)d_ws;                    // bf16 workspace
  ushort* Kt = Qt + (size_t)BHD * LL * 32;
  ushort* Vt = Kt + (size_t)BHD * LL * 32;

  qkv_kernel <<<dim3(BHD, 8), 256, 0, stream>>>(x, wq, wk, wv, Qt, Kt, Vt);
  attn_kernel<<<dim3(BHD, 8), 256, 0, stream>>>(x, Qt, Kt, Vt, d_out);
}

// Round 8
// 113.080 us; speedup vs baseline: 1.1827x; 1.1315x over previous
//
#include <hip/hip_runtime.h>

#define LL   1024
#define BHD  128   // B*heads = 16*8
#define LOG2E 1.44269504088896340736f

typedef unsigned int       uint;
typedef unsigned short     ushort;
typedef unsigned long long ull;

typedef __attribute__((ext_vector_type(8)))  __bf16          bf16x8;
typedef __attribute__((ext_vector_type(8)))  unsigned short  u16x8;
typedef __attribute__((ext_vector_type(4)))  unsigned short  u16x4;
typedef __attribute__((ext_vector_type(4)))  uint            ui32x4;
typedef __attribute__((ext_vector_type(4)))  float           f32x4;
typedef __attribute__((ext_vector_type(16))) float           f32x16;

static __device__ __forceinline__ ushort f2bf(float f){
  union {float f; uint u;} v; v.f = f;
  uint u = v.u + 0x7fffu + ((v.u >> 16) & 1u);  // RNE
  return (ushort)(u >> 16);
}
static __device__ __forceinline__ uint pack2(float a, float b){
  return (uint)f2bf(a) | ((uint)f2bf(b) << 16);
}
// truncating pack: one v_perm
static __device__ __forceinline__ uint packtrunc(float a, float b){
  union {float f; uint u;} x, y; x.f = a; y.f = b;
  return __builtin_amdgcn_perm(y.u, x.u, 0x07060302u);
}
static __device__ __forceinline__ bf16x8 ld_frag(const ushort* p){
  u16x8 t = *(const u16x8*)p;
  return __builtin_bit_cast(bf16x8, t);
}
// 8-elem frag via two b64 reads (for 8B-aligned pitches)
static __device__ __forceinline__ bf16x8 ld_frag64(const ushort* p){
  u16x4 a = *(const u16x4*)p;
  u16x4 b = *(const u16x4*)(p + 4);
  u16x8 t;
  t[0]=a[0]; t[1]=a[1]; t[2]=a[2]; t[3]=a[3];
  t[4]=b[0]; t[5]=b[1]; t[6]=b[2]; t[7]=b[3];
  return __builtin_bit_cast(bf16x8, t);
}

// bf16 vs fp32 sniff on x (deterministic, graph-safe).
static __device__ __forceinline__ bool sniff_is_bf16(const uint* xw, int tid, int* cnt){
  uint w = xw[tid & 255];
  uint e = (w >> 7) & 0xFFu;
  bool hit = (e >= 118u) && (e <= 132u);
  ull b = __ballot(hit);
  if ((tid & 63) == 0) cnt[tid >> 6] = __popcll(b);
  __syncthreads();
  bool r = (cnt[0] + cnt[1] + cnt[2] + cnt[3]) > 128;
  __syncthreads();
  return r;
}

// ---------------------------------------------------------------------------
// Kernel 1: grouped 1x1 conv via MFMA.
// Q (D[m=l][n=d]) -> Qt[bh][l][32]  key-major
// K (D[m=l][n=d]) -> Kt[bh][l][32]  key-major, + PE, *log2e
// V (D[m=d][n=l], swapped operands) -> Vt[bh][d][1024] d-major
// ---------------------------------------------------------------------------
__global__ __launch_bounds__(256) void qkv_kernel(
    const void* __restrict__ xr,
    const void* __restrict__ wqr,
    const void* __restrict__ wkr,
    const void* __restrict__ wvr,
    ushort* __restrict__ Qt, ushort* __restrict__ Kt, ushort* __restrict__ Vt)
{
  const int bh   = blockIdx.x;
  const int lt   = blockIdx.y;          // 0..7, 128-l tiles
  const int tid  = threadIdx.x;
  const int wave = tid >> 6;
  const int lane = tid & 63;
  const int l16  = lane & 15;
  const int quad = lane >> 4;
  const int lbase = lt * 128;

  __shared__ int cnt[4];
  __shared__ __align__(16) uint xsd[128][20];   // dword c-pairs, 80B rows

  const bool is_bf = sniff_is_bf16((const uint*)xr, tid, cnt);

  { // stage + transpose x tile: thread = (c-pair, 8-l group)
    const int cp = tid & 15, lg = tid >> 4;
    const size_t rb = (size_t)(bh*32 + 2*cp)*LL + lbase + lg*8;
    uint dw[8];
    if (is_bf){
      u16x8 e = *(const u16x8*)((const ushort*)xr + rb);
      u16x8 o = *(const u16x8*)((const ushort*)xr + rb + LL);
      #pragma unroll
      for (int j = 0; j < 8; ++j) dw[j] = (uint)e[j] | ((uint)o[j] << 16);
    } else {
      const float* xf = (const float*)xr;
      float4 e0 = *(const float4*)(xf + rb);
      float4 e1 = *(const float4*)(xf + rb + 4);
      float4 o0 = *(const float4*)(xf + rb + LL);
      float4 o1 = *(const float4*)(xf + rb + LL + 4);
      dw[0]=pack2(e0.x,o0.x); dw[1]=pack2(e0.y,o0.y);
      dw[2]=pack2(e0.z,o0.z); dw[3]=pack2(e0.w,o0.w);
      dw[4]=pack2(e1.x,o1.x); dw[5]=pack2(e1.y,o1.y);
      dw[6]=pack2(e1.z,o1.z); dw[7]=pack2(e1.w,o1.w);
    }
    #pragma unroll
    for (int j = 0; j < 8; ++j) xsd[lg*8 + j][cp] = dw[j];
  }
  __syncthreads();

  const void* wsrc[3] = {wqr, wkr, wvr};
  bf16x8 bw[3][2];
  #pragma unroll
  for (int p = 0; p < 3; ++p)
    #pragma unroll
    for (int nh = 0; nh < 2; ++nh){
      const int row = (bh & 7)*32 + nh*16 + l16;
      if (is_bf){
        bw[p][nh] = ld_frag((const ushort*)wsrc[p] + (size_t)row*32 + quad*8);
      } else {
        const float* wf = (const float*)wsrc[p] + (size_t)row*32 + quad*8;
        float4 f0 = *(const float4*)wf, f1 = *(const float4*)(wf + 4);
        u16x8 t;
        t[0]=f2bf(f0.x); t[1]=f2bf(f0.y); t[2]=f2bf(f0.z); t[3]=f2bf(f0.w);
        t[4]=f2bf(f1.x); t[5]=f2bf(f1.y); t[6]=f2bf(f1.z); t[7]=f2bf(f1.w);
        bw[p][nh] = __builtin_bit_cast(bf16x8, t);
      }
    }

  bf16x8 ax[2];
  #pragma unroll
  for (int mt = 0; mt < 2; ++mt)
    ax[mt] = __builtin_bit_cast(bf16x8,
               *(const ui32x4*)&xsd[wave*32 + mt*16 + l16][quad*4]);

  const f32x4 z = {0.f,0.f,0.f,0.f};
  f32x4 dq[2][2], dk[2][2], dv[2][2];
  #pragma unroll
  for (int mt = 0; mt < 2; ++mt)
    #pragma unroll
    for (int nh = 0; nh < 2; ++nh){
      dq[mt][nh] = __builtin_amdgcn_mfma_f32_16x16x32_bf16(ax[mt], bw[0][nh], z, 0,0,0);
      dk[mt][nh] = __builtin_amdgcn_mfma_f32_16x16x32_bf16(ax[mt], bw[1][nh], z, 0,0,0);
      dv[nh][mt] = __builtin_amdgcn_mfma_f32_16x16x32_bf16(bw[2][nh], ax[mt], z, 0,0,0);
    }

  // Q stores: lane holds l = quad*4+r, d = nh*16+l16 -> Qt[l][d]
  #pragma unroll
  for (int mt = 0; mt < 2; ++mt)
    #pragma unroll
    for (int nh = 0; nh < 2; ++nh)
      #pragma unroll
      for (int r = 0; r < 4; ++r){
        const int l = lbase + wave*32 + mt*16 + quad*4 + r;
        const int d = nh*16 + l16;
        Qt[((size_t)bh*LL + l)*32 + d] = f2bf(dq[mt][nh][r]);
      }
  // K stores (key-major): + sine PE (fp32), then *log2e
  #pragma unroll
  for (int mt = 0; mt < 2; ++mt)
    #pragma unroll
    for (int nh = 0; nh < 2; ++nh){
      const int d = nh*16 + l16;
      const int c = (bh & 7)*32 + d;
      const float freq = __expf(-0.03597789207f * (float)(c & ~1));
      #pragma unroll
      for (int r = 0; r < 4; ++r){
        const int l = lbase + wave*32 + mt*16 + quad*4 + r;
        const float ang = freq * (float)l;
        const float pe  = (c & 1) ? __cosf(ang) : __sinf(ang);
        Kt[((size_t)bh*LL + l)*32 + d] = f2bf((dk[mt][nh][r] + pe) * LOG2E);
      }
    }
  // V stores (d-major)
  #pragma unroll
  for (int dh = 0; dh < 2; ++dh)
    #pragma unroll
    for (int mt = 0; mt < 2; ++mt)
      #pragma unroll
      for (int r = 0; r < 4; ++r){
        const int d = dh*16 + quad*4 + r;
        const int l = lbase + wave*32 + mt*16 + l16;
        Vt[((size_t)(bh*32 + d))*LL + l] = f2bf(dv[dh][mt][r]);
      }
}

// ---------------------------------------------------------------------------
// Kernel 2: flash attention on 32x32x16 MFMAs. Block = (bh, 128-q), 4 waves
// x 32 q. S^T tiles: C col = lane&31 = q; P reaches the PV B-operand via one
// half-wave shfl_xor(32) per 16-key chunk (no LDS round-trip). O^T = V*P^T.
// exp2 via raw v_exp_f32 (args bounded, no OCML edge handling needed).
// Ks: 80B pitch + seg rotation. Vs: 136B pitch (bank stride 2 = free), b64.
// ---------------------------------------------------------------------------
__global__ __launch_bounds__(256, 4) void attn_kernel(
    const void*   __restrict__ xr,     // dtype sniff only (output format)
    const ushort* __restrict__ Qt,
    const ushort* __restrict__ Kt,
    const ushort* __restrict__ Vt,
    void* __restrict__ out)
{
  const int bh  = blockIdx.x;
  const int qt  = blockIdx.y;          // 0..7 (128 q per block)
  const int tid = threadIdx.x;
  const int wave = tid >> 6;
  const int lane = tid & 63;
  const int q32  = lane & 31;
  const int h    = lane >> 5;

  __shared__ int cnt[4];
  __shared__ __align__(16) ushort Ks[64][40];   // 80B rows, seg-rotated
  __shared__ __align__(16) ushort Vs[32][68];   // 136B rows: bank stride 2

  const bool is_bf = sniff_is_bf16((const uint*)xr, tid, cnt);

  // Q B-frags: n = q = lane&31, k = c*16 + 8h + j
  const int qg = qt*128 + wave*32 + q32;
  const ushort* qrow = Qt + ((size_t)bh*LL + qg)*32;
  bf16x8 bq0 = ld_frag(qrow + h*8);
  bf16x8 bq1 = ld_frag(qrow + 16 + h*8);

  // staging: K: thread=(key 0..63, seg 0..3); V: thread=(d 0..31, g 0..7)
  const int skey = tid >> 2, sseg = tid & 3;
  const int sp = (sseg + (skey >> 2)) & 3;             // seg rotation
  const ushort* kg = Kt + ((size_t)(bh*LL + skey))*32 + sseg*8;
  ushort* kw = &Ks[skey][sp*8];
  const int sd = tid >> 3, sg = tid & 7;
  const ushort* vg = Vt + ((size_t)(bh*32 + sd))*LL + sg*8;
  ushort* vw = &Vs[sd][sg*8];

  // A-frag read pointers (rotation matches write: rot = (row>>2)&3)
  const int rot = (q32 >> 2) & 3;
  const ushort* ka0 = &Ks[q32][((h + rot) & 3)*8];       // c'=0
  const ushort* ka1 = &Ks[q32][((2 + h + rot) & 3)*8];   // c'=1
  const ushort* vr  = &Vs[q32][h*8];                     // + 16*c per chunk

  f32x16 O = {};
  float rsum = 0.f;

  u16x8 kreg = *(const u16x8*)kg;
  u16x8 vreg = *(const u16x8*)vg;

  for (int kt = 0; kt < 16; ++kt){
    __syncthreads();                 // previous tile fully consumed
    *(u16x8*)kw = kreg;
    { u16x4 lo, hi;
      lo[0]=vreg[0]; lo[1]=vreg[1]; lo[2]=vreg[2]; lo[3]=vreg[3];
      hi[0]=vreg[4]; hi[1]=vreg[5]; hi[2]=vreg[6]; hi[3]=vreg[7];
      *(u16x4*)vw = lo; *(u16x4*)(vw + 4) = hi; }
    __syncthreads();                 // tile kt ready
    if (kt < 15){                    // prefetch kt+1 (hidden by compute)
      kreg = *(const u16x8*)(kg + (size_t)(kt+1)*64*32);
      vreg = *(const u16x8*)(vg + (kt+1)*64);
    }

    // S^T: D[m=key][n=q], 2 tiles of 32 keys, K=32 via 2 chained MFMAs
    f32x16 st[2];
    #pragma unroll
    for (int t = 0; t < 2; ++t){
      bf16x8 a0 = ld_frag(ka0 + t*32*40);
      bf16x8 a1 = ld_frag(ka1 + t*32*40);
      f32x16 zz = {};
      f32x16 s  = __builtin_amdgcn_mfma_f32_32x32x16_bf16(a0, bq0, zz, 0,0,0);
      st[t]     = __builtin_amdgcn_mfma_f32_32x32x16_bf16(a1, bq1, s,  0,0,0);
    }

    // softmax (no max; |scores*log2e| << 127): raw v_exp_f32
    uint pr[2][8];
    #pragma unroll
    for (int t = 0; t < 2; ++t)
      #pragma unroll
      for (int zi = 0; zi < 8; ++zi){
        float p0 = __builtin_amdgcn_exp2f(st[t][2*zi]);
        float p1 = __builtin_amdgcn_exp2f(st[t][2*zi+1]);
        rsum += p0 + p1;
        pr[t][zi] = packtrunc(p0, p1);
      }

    // O^T += V * P^T over 4 chunks of 16 keys
    #pragma unroll
    for (int c = 0; c < 4; ++c){
      const int t = c >> 1, g0 = 4*(c & 1);
      uint s0 = h ? pr[t][g0+0] : pr[t][g0+2];
      uint s1 = h ? pr[t][g0+1] : pr[t][g0+3];
      uint r0 = (uint)__shfl_xor((int)s0, 32);
      uint r1 = (uint)__shfl_xor((int)s1, 32);
      ui32x4 pb;
      pb[0] = h ? r0 : pr[t][g0+0];
      pb[1] = h ? r1 : pr[t][g0+1];
      pb[2] = h ? pr[t][g0+2] : r0;
      pb[3] = h ? pr[t][g0+3] : r1;
      bf16x8 va = ld_frag64(vr + c*16);
      O = __builtin_amdgcn_mfma_f32_32x32x16_bf16(
            va, __builtin_bit_cast(bf16x8, pb), O, 0,0,0);
    }
  }

  // lane holds keys with bit2==h; partner holds the rest
  rsum += __shfl_xor(rsum, 32);
  const float inv = 1.f / rsum;

  // epilogue: D[m=d][n=q]: d = (reg&3)+8(reg>>2)+4h, q = lane&31 (coalesced)
  #pragma unroll
  for (int reg = 0; reg < 16; ++reg){
    const int d = (reg & 3) + 8*(reg >> 2) + 4*h;
    const float v = O[reg] * inv;
    const size_t off = ((size_t)(bh*32 + d))*LL + qg;
    if (is_bf) ((ushort*)out)[off] = f2bf(v);
    else       ((float*)out)[off]  = v;
  }
}

extern "C" void kernel_launch(void* const* d_in, const int* in_sizes, int n_in,
                              void* d_out, int out_size, void* d_ws, size_t ws_size,
                              hipStream_t stream) {
  const void* x  = d_in[0];
  const void* wq = d_in[1];
  const void* wk = d_in[2];
  const void* wv = d_in[3];

  ushort* Qt = (ushort*)d_ws;                    // bf16 workspace
  ushort* Kt = Qt + (size_t)BHD * LL * 32;
  ushort* Vt = Kt + (size_t)BHD * LL * 32;

  qkv_kernel <<<dim3(BHD, 8), 256, 0, stream>>>(x, wq, wk, wv, Qt, Kt, Vt);
  attn_kernel<<<dim3(BHD, 8), 256, 0, stream>>>(x, Qt, Kt, Vt, d_out);
}